// Round 13
// baseline (79.138 us; speedup 1.0000x reference)
//
#include <hip/hip_runtime.h>
#include <hip/hip_fp16.h>

typedef float f4 __attribute__((ext_vector_type(4)));
typedef float f32x4 __attribute__((ext_vector_type(4)));
typedef _Float16 f16x8 __attribute__((ext_vector_type(8)));
typedef unsigned int u32x4 __attribute__((ext_vector_type(4)));

#define NPTS 262144
#define CDIM 48
#define DDIM 32
#define KDIM 4
#define G0 512
#define G1 512
#define G2 128

#define TPB_TILES 4   // 64-point tiles per block; one WB restage serves 4 tiles

// ws layout (ushort slots) — identical geometry to R12, values now f16:
// [0, 18432)   : WB — f16 MFMA fragments (36864 B)
//                frag f = (plane*2 + dtile)*6 + kt ; entry f*512 + lane*8 + j
//                value = tw[k] * feat_plane[id[k]][c][d],
//                kc = kt*32 + (lane>>4)*8 + j, k=kc/48, c=kc%48, d=dtile*16+(lane&15)
// T tables in f16, layout [k][g][c]:
#define T0_OFF 18432                     // 4*512*48 = 98304
#define T1_OFF (18432 + 98304)           // 98304
#define T2_OFF (18432 + 2 * 98304)       // 4*128*48 = 24576

static __forceinline__ __device__ unsigned short f2h(float f) {
    _Float16 h = (_Float16)f;   // RNE
    return __builtin_bit_cast(unsigned short, h);
}
static __forceinline__ __device__ __half2 h2(unsigned int u) {
    return __builtin_bit_cast(__half2, u);
}
static __forceinline__ __device__ unsigned int h2u(__half2 h) {
    return __builtin_bit_cast(unsigned int, h);
}

__global__ void pack_kernel(const int* __restrict__ topk_id,
                            const float* __restrict__ tw,
                            const float* __restrict__ line0,
                            const float* __restrict__ line1,
                            const float* __restrict__ line2,
                            const float* __restrict__ feat0,
                            const float* __restrict__ feat1,
                            const float* __restrict__ feat2,
                            unsigned short* __restrict__ ws) {
    int tid = blockIdx.x * blockDim.x + threadIdx.x;
    int stride = gridDim.x * blockDim.x;

    for (int idx = tid; idx < 3 * 2 * 6 * 64 * 8; idx += stride) {
        int j = idx & 7;
        int l = (idx >> 3) & 63;
        int kt = (idx >> 9) % 6;
        int t = (idx / 3072) % 2;
        int i = idx / 6144;
        int kc = kt * 32 + (l >> 4) * 8 + j;
        int k = kc / 48;
        int c = kc - k * 48;
        int d = t * 16 + (l & 15);
        const float* f = (i == 0) ? feat0 : (i == 1) ? feat1 : feat2;
        float val = tw[k] * f[((size_t)topk_id[k] * CDIM + c) * DDIM + d];
        ws[idx] = f2h(val);
    }
    for (int idx = tid; idx < KDIM * G0 * CDIM; idx += stride) {
        int c = idx % CDIM;
        int g = (idx / CDIM) % G0;
        int k = idx / (CDIM * G0);
        int src = (topk_id[k] * CDIM + c) * G0 + g;
        ws[T0_OFF + idx] = f2h(line0[src]);
        ws[T1_OFF + idx] = f2h(line1[src]);
    }
    for (int idx = tid; idx < KDIM * G2 * CDIM; idx += stride) {
        int c = idx % CDIM;
        int g = (idx / CDIM) % G2;
        int k = idx / (CDIM * G2);
        ws[T2_OFF + idx] = f2h(line2[(topk_id[k] * CDIM + c) * G2 + g]);
    }
}

__global__ __launch_bounds__(256, 3) void main_kernel(const float* __restrict__ pts,
                                                      const unsigned short* __restrict__ ws,
                                                      float* __restrict__ out) {
    __shared__ __align__(16) unsigned short sWB[18432];   // 36864 B
    {
        const u32x4* src = (const u32x4*)ws;
        u32x4* dst = (u32x4*)sWB;
        for (int i = threadIdx.x; i < 2304; i += 256) dst[i] = src[i];
    }
    __syncthreads();

    const int lane = threadIdx.x & 63;
    const int wave = threadIdx.x >> 6;
    const int row = lane & 15;     // point within the wave's 16-point tile
    const int h = lane >> 4;       // k-chunk selector (and d-subblock at epilogue)

    const unsigned short* T0 = ws + T0_OFF;
    const unsigned short* T1 = ws + T1_OFF;
    const unsigned short* T2 = ws + T2_OFF;
    const u32x4* wb = (const u32x4*)sWB;

    for (int tile = 0; tile < TPB_TILES; ++tile) {
        const int base = (blockIdx.x * TPB_TILES + tile) * 64 + wave * 16;
        const int p = base + row;

        const float px = pts[p * 3 + 0];
        const float py = pts[p * 3 + 1];
        const float pz = pts[p * 3 + 2];

        float pos0 = (px + 1.0f) * (0.5f * (float)(G0 - 1));
        int i00 = min(max((int)floorf(pos0), 0), G0 - 2);
        float w0 = pos0 - (float)i00;

        float pos1 = (py + 1.0f) * (0.5f * (float)(G1 - 1));
        int i01 = min(max((int)floorf(pos1), 0), G1 - 2);
        float w1 = pos1 - (float)i01;

        float pos2 = (pz + 1.0f) * (0.5f * (float)(G2 - 1));
        int i02 = min(max((int)floorf(pos2), 0), G2 - 2);
        float w2 = pos2 - (float)i02;

        // packed-f16 interpolation coefficients
        const __half2 W0 = __float2half2_rn(w0), OM0 = __float2half2_rn(1.0f - w0);
        const __half2 W1 = __float2half2_rn(w1), OM1 = __float2half2_rn(1.0f - w1);
        const __half2 W2 = __float2half2_rn(w2), OM2 = __float2half2_rn(1.0f - w2);

        f32x4 acc00 = {0.f, 0.f, 0.f, 0.f}, acc01 = acc00;
        f32x4 acc10 = acc00, acc11 = acc00;
        f32x4 acc20 = acc00, acc21 = acc00;

#define DECL_LD(n) u32x4 n##a0, n##b0, n##a1, n##b1, n##a2, n##b2
#define LOADKT(n, KT) {                                                        \
        int kc_ = (KT) * 32 + h * 8;                                           \
        int k_ = kc_ / 48;                                                     \
        int c_ = kc_ - k_ * 48;                                                \
        const unsigned short* t0_ = T0 + (k_ * G0 + i00) * CDIM + c_;          \
        const unsigned short* t1_ = T1 + (k_ * G1 + i01) * CDIM + c_;          \
        const unsigned short* t2_ = T2 + (k_ * G2 + i02) * CDIM + c_;          \
        n##a0 = *(const u32x4*)t0_;  n##b0 = *(const u32x4*)(t0_ + CDIM);      \
        n##a1 = *(const u32x4*)t1_;  n##b1 = *(const u32x4*)(t1_ + CDIM);      \
        n##a2 = *(const u32x4*)t2_;  n##b2 = *(const u32x4*)(t2_ + CDIM); }
// Keep-alive fence (R10-proven): forces the batch's 18 loaded values to be
// materialized in VGPRs here -> loads issue together, one waitcnt.
#define KEEP18(a, b, c)                                                        \
    asm volatile("" : "+v"(a##a0), "+v"(a##b0), "+v"(a##a1), "+v"(a##b1),      \
                      "+v"(a##a2), "+v"(a##b2),                                \
                      "+v"(b##a0), "+v"(b##b0), "+v"(b##a1), "+v"(b##b1),      \
                      "+v"(b##a2), "+v"(b##b2),                                \
                      "+v"(c##a0), "+v"(c##b0), "+v"(c##a1), "+v"(c##b1),      \
                      "+v"(c##a2), "+v"(c##b2))
// Packed-f16 compute: per dword j (2 k-slots): 6 pk lerp ops + 3 pk muls.
// Products land already packed in MFMA f16 operand order (dword j = slots
// 2j,2j+1 — little-endian low half = even slot, matching WB pack order).
#define COMPUTEKT(n, KT) {                                                     \
        u32x4 pa01, pa02, pa12;                                                \
        _Pragma("unroll")                                                      \
        for (int j = 0; j < 4; ++j) {                                          \
            __half2 x0 = __hfma2(h2(n##b0[j]), W0, __hmul2(h2(n##a0[j]), OM0));\
            __half2 x1 = __hfma2(h2(n##b1[j]), W1, __hmul2(h2(n##a1[j]), OM1));\
            __half2 x2 = __hfma2(h2(n##b2[j]), W2, __hmul2(h2(n##a2[j]), OM2));\
            pa01[j] = h2u(__hmul2(x0, x1));                                    \
            pa02[j] = h2u(__hmul2(x0, x2));                                    \
            pa12[j] = h2u(__hmul2(x1, x2));                                    \
        }                                                                      \
        f16x8 fa01 = __builtin_bit_cast(f16x8, pa01);                          \
        f16x8 fa02 = __builtin_bit_cast(f16x8, pa02);                          \
        f16x8 fa12 = __builtin_bit_cast(f16x8, pa12);                          \
        acc00 = __builtin_amdgcn_mfma_f32_16x16x32_f16(__builtin_bit_cast(f16x8, wb[(0 * 6 + (KT)) * 64 + lane]), fa01, acc00, 0, 0, 0); \
        acc01 = __builtin_amdgcn_mfma_f32_16x16x32_f16(__builtin_bit_cast(f16x8, wb[(1 * 6 + (KT)) * 64 + lane]), fa01, acc01, 0, 0, 0); \
        acc10 = __builtin_amdgcn_mfma_f32_16x16x32_f16(__builtin_bit_cast(f16x8, wb[(2 * 6 + (KT)) * 64 + lane]), fa02, acc10, 0, 0, 0); \
        acc11 = __builtin_amdgcn_mfma_f32_16x16x32_f16(__builtin_bit_cast(f16x8, wb[(3 * 6 + (KT)) * 64 + lane]), fa02, acc11, 0, 0, 0); \
        acc20 = __builtin_amdgcn_mfma_f32_16x16x32_f16(__builtin_bit_cast(f16x8, wb[(4 * 6 + (KT)) * 64 + lane]), fa12, acc20, 0, 0, 0); \
        acc21 = __builtin_amdgcn_mfma_f32_16x16x32_f16(__builtin_bit_cast(f16x8, wb[(5 * 6 + (KT)) * 64 + lane]), fa12, acc21, 0, 0, 0); }

        DECL_LD(q0); DECL_LD(q1); DECL_LD(q2);
        DECL_LD(q3); DECL_LD(q4); DECL_LD(q5);

        // Batch 1: 18 independent 16B gathers in flight, one fence.
        LOADKT(q0, 0); LOADKT(q1, 1); LOADKT(q2, 2);
        KEEP18(q0, q1, q2);
        // Batch 2 issues while batch 1 is consumed.
        LOADKT(q3, 3); LOADKT(q4, 4); LOADKT(q5, 5);

        COMPUTEKT(q0, 0);
        COMPUTEKT(q1, 1);
        COMPUTEKT(q2, 2);

        KEEP18(q3, q4, q5);

        COMPUTEKT(q3, 3);
        COMPUTEKT(q4, 4);
        COMPUTEKT(q5, 5);

#undef DECL_LD
#undef LOADKT
#undef KEEP18
#undef COMPUTEKT

        // Epilogue (R8): lane owns point base+row, d-block h*4.. of each
        // 16-wide dtile -> 6 float4 stores, per-point-contiguous 64B segments.
        {
            float* o = out + (size_t)(base + row) * 96 + h * 4;
            *(f4*)(o + 0)  = acc00;
            *(f4*)(o + 16) = acc01;
            *(f4*)(o + 32) = acc10;
            *(f4*)(o + 48) = acc11;
            *(f4*)(o + 64) = acc20;
            *(f4*)(o + 80) = acc21;
        }
    }
}

extern "C" void kernel_launch(void* const* d_in, const int* in_sizes, int n_in,
                              void* d_out, int out_size, void* d_ws, size_t ws_size,
                              hipStream_t stream) {
    const float* pts = (const float*)d_in[0];
    const int* topk_id = (const int*)d_in[1];
    const float* tw = (const float*)d_in[2];
    const float* line0 = (const float*)d_in[3];
    const float* line1 = (const float*)d_in[4];
    const float* line2 = (const float*)d_in[5];
    const float* feat0 = (const float*)d_in[6];
    const float* feat1 = (const float*)d_in[7];
    const float* feat2 = (const float*)d_in[8];
    float* out = (float*)d_out;
    unsigned short* ws = (unsigned short*)d_ws;

    pack_kernel<<<512, 256, 0, stream>>>(topk_id, tw, line0, line1, line2,
                                         feat0, feat1, feat2, ws);
    main_kernel<<<NPTS / (64 * TPB_TILES), 256, 0, stream>>>(pts, ws, out);
}

// Round 14
// 70.234 us; speedup vs baseline: 1.1268x; 1.1268x over previous
//
#include <hip/hip_runtime.h>
#include <hip/hip_fp16.h>

typedef float f4 __attribute__((ext_vector_type(4)));
typedef float f32x4 __attribute__((ext_vector_type(4)));
typedef _Float16 f16x8 __attribute__((ext_vector_type(8)));
typedef unsigned int u32x4 __attribute__((ext_vector_type(4)));

#define NPTS 262144
#define CDIM 48
#define DDIM 32
#define KDIM 4
#define G0 512
#define G1 512
#define G2 128

#define TPB_TILES 4   // 64-point tiles per block; one WB restage serves 4 tiles

// ws layout (ushort slots) — R13 geometry, f16 values:
// [0, 18432)   : WB — f16 MFMA fragments (36864 B)
// T tables in f16, layout [k][g][c]:
#define T0_OFF 18432                     // 4*512*48 = 98304
#define T1_OFF (18432 + 98304)           // 98304
#define T2_OFF (18432 + 2 * 98304)       // 4*128*48 = 24576

static __forceinline__ __device__ unsigned short f2h(float f) {
    _Float16 h = (_Float16)f;   // RNE
    return __builtin_bit_cast(unsigned short, h);
}
static __forceinline__ __device__ __half2 h2(unsigned int u) {
    return __builtin_bit_cast(__half2, u);
}
static __forceinline__ __device__ unsigned int h2u(__half2 h) {
    return __builtin_bit_cast(unsigned int, h);
}

__global__ void pack_kernel(const int* __restrict__ topk_id,
                            const float* __restrict__ tw,
                            const float* __restrict__ line0,
                            const float* __restrict__ line1,
                            const float* __restrict__ line2,
                            const float* __restrict__ feat0,
                            const float* __restrict__ feat1,
                            const float* __restrict__ feat2,
                            unsigned short* __restrict__ ws) {
    int tid = blockIdx.x * blockDim.x + threadIdx.x;
    int stride = gridDim.x * blockDim.x;

    for (int idx = tid; idx < 3 * 2 * 6 * 64 * 8; idx += stride) {
        int j = idx & 7;
        int l = (idx >> 3) & 63;
        int kt = (idx >> 9) % 6;
        int t = (idx / 3072) % 2;
        int i = idx / 6144;
        int kc = kt * 32 + (l >> 4) * 8 + j;
        int k = kc / 48;
        int c = kc - k * 48;
        int d = t * 16 + (l & 15);
        const float* f = (i == 0) ? feat0 : (i == 1) ? feat1 : feat2;
        float val = tw[k] * f[((size_t)topk_id[k] * CDIM + c) * DDIM + d];
        ws[idx] = f2h(val);
    }
    for (int idx = tid; idx < KDIM * G0 * CDIM; idx += stride) {
        int c = idx % CDIM;
        int g = (idx / CDIM) % G0;
        int k = idx / (CDIM * G0);
        int src = (topk_id[k] * CDIM + c) * G0 + g;
        ws[T0_OFF + idx] = f2h(line0[src]);
        ws[T1_OFF + idx] = f2h(line1[src]);
    }
    for (int idx = tid; idx < KDIM * G2 * CDIM; idx += stride) {
        int c = idx % CDIM;
        int g = (idx / CDIM) % G2;
        int k = idx / (CDIM * G2);
        ws[T2_OFF + idx] = f2h(line2[(topk_id[k] * CDIM + c) * G2 + g]);
    }
}

__global__ __launch_bounds__(256, 2) void main_kernel(const float* __restrict__ pts,
                                                      const unsigned short* __restrict__ ws,
                                                      float* __restrict__ out) {
    __shared__ __align__(16) unsigned short sWB[18432];   // 36864 B

    const int lane = threadIdx.x & 63;
    const int wave = threadIdx.x >> 6;
    const int row = lane & 15;     // point within the wave's 16-point tile
    const int h = lane >> 4;       // k-chunk selector (and d-subblock at epilogue)

    // Prefetch ALL 4 tiles' pts up front; latency hides under the restage.
    float P0x, P0y, P0z, P1x, P1y, P1z, P2x, P2y, P2z, P3x, P3y, P3z;
    {
        const int pb = blockIdx.x * TPB_TILES * 64 + wave * 16 + row;
        P0x = pts[(pb + 0 * 64) * 3 + 0]; P0y = pts[(pb + 0 * 64) * 3 + 1]; P0z = pts[(pb + 0 * 64) * 3 + 2];
        P1x = pts[(pb + 1 * 64) * 3 + 0]; P1y = pts[(pb + 1 * 64) * 3 + 1]; P1z = pts[(pb + 1 * 64) * 3 + 2];
        P2x = pts[(pb + 2 * 64) * 3 + 0]; P2y = pts[(pb + 2 * 64) * 3 + 1]; P2z = pts[(pb + 2 * 64) * 3 + 2];
        P3x = pts[(pb + 3 * 64) * 3 + 0]; P3y = pts[(pb + 3 * 64) * 3 + 1]; P3z = pts[(pb + 3 * 64) * 3 + 2];
    }
    asm volatile("" : "+v"(P0x), "+v"(P0y), "+v"(P0z), "+v"(P1x), "+v"(P1y), "+v"(P1z),
                      "+v"(P2x), "+v"(P2y), "+v"(P2z), "+v"(P3x), "+v"(P3y), "+v"(P3z));

    {
        const u32x4* src = (const u32x4*)ws;
        u32x4* dst = (u32x4*)sWB;
        for (int i = threadIdx.x; i < 2304; i += 256) dst[i] = src[i];
    }
    __syncthreads();

    const unsigned short* T0 = ws + T0_OFF;
    const unsigned short* T1 = ws + T1_OFF;
    const unsigned short* T2 = ws + T2_OFF;
    const u32x4* wb = (const u32x4*)sWB;

#pragma unroll
    for (int tile = 0; tile < TPB_TILES; ++tile) {
        const int base = (blockIdx.x * TPB_TILES + tile) * 64 + wave * 16;

        const float px = (tile == 0) ? P0x : (tile == 1) ? P1x : (tile == 2) ? P2x : P3x;
        const float py = (tile == 0) ? P0y : (tile == 1) ? P1y : (tile == 2) ? P2y : P3y;
        const float pz = (tile == 0) ? P0z : (tile == 1) ? P1z : (tile == 2) ? P2z : P3z;

        float pos0 = (px + 1.0f) * (0.5f * (float)(G0 - 1));
        int i00 = min(max((int)floorf(pos0), 0), G0 - 2);
        float w0 = pos0 - (float)i00;

        float pos1 = (py + 1.0f) * (0.5f * (float)(G1 - 1));
        int i01 = min(max((int)floorf(pos1), 0), G1 - 2);
        float w1 = pos1 - (float)i01;

        float pos2 = (pz + 1.0f) * (0.5f * (float)(G2 - 1));
        int i02 = min(max((int)floorf(pos2), 0), G2 - 2);
        float w2 = pos2 - (float)i02;

        const __half2 W0 = __float2half2_rn(w0), OM0 = __float2half2_rn(1.0f - w0);
        const __half2 W1 = __float2half2_rn(w1), OM1 = __float2half2_rn(1.0f - w1);
        const __half2 W2 = __float2half2_rn(w2), OM2 = __float2half2_rn(1.0f - w2);

        f32x4 acc00 = {0.f, 0.f, 0.f, 0.f}, acc01 = acc00;
        f32x4 acc10 = acc00, acc11 = acc00;
        f32x4 acc20 = acc00, acc21 = acc00;

#define DECL_LD(n) u32x4 n##a0, n##b0, n##a1, n##b1, n##a2, n##b2
#define LOADKT(n, KT) {                                                        \
        int kc_ = (KT) * 32 + h * 8;                                           \
        int k_ = kc_ / 48;                                                     \
        int c_ = kc_ - k_ * 48;                                                \
        const unsigned short* t0_ = T0 + (k_ * G0 + i00) * CDIM + c_;          \
        const unsigned short* t1_ = T1 + (k_ * G1 + i01) * CDIM + c_;          \
        const unsigned short* t2_ = T2 + (k_ * G2 + i02) * CDIM + c_;          \
        n##a0 = *(const u32x4*)t0_;  n##b0 = *(const u32x4*)(t0_ + CDIM);      \
        n##a1 = *(const u32x4*)t1_;  n##b1 = *(const u32x4*)(t1_ + CDIM);      \
        n##a2 = *(const u32x4*)t2_;  n##b2 = *(const u32x4*)(t2_ + CDIM); }
// SINGLE merged fence for all 36 loads of the tile: every value must be
// materialized here -> backend must allocate BOTH 18-load windows and issue
// all loads before ONE waitcnt (R12's late KEEP let the scheduler sink
// batch2 and exposed a second serialized latency).
#define KEEP36()                                                               \
    asm volatile("" : "+v"(q0a0), "+v"(q0b0), "+v"(q0a1), "+v"(q0b1),          \
                      "+v"(q0a2), "+v"(q0b2),                                  \
                      "+v"(q1a0), "+v"(q1b0), "+v"(q1a1), "+v"(q1b1),          \
                      "+v"(q1a2), "+v"(q1b2),                                  \
                      "+v"(q2a0), "+v"(q2b0), "+v"(q2a1), "+v"(q2b1),          \
                      "+v"(q2a2), "+v"(q2b2),                                  \
                      "+v"(q3a0), "+v"(q3b0), "+v"(q3a1), "+v"(q3b1),          \
                      "+v"(q3a2), "+v"(q3b2),                                  \
                      "+v"(q4a0), "+v"(q4b0), "+v"(q4a1), "+v"(q4b1),          \
                      "+v"(q4a2), "+v"(q4b2),                                  \
                      "+v"(q5a0), "+v"(q5b0), "+v"(q5a1), "+v"(q5b1),          \
                      "+v"(q5a2), "+v"(q5b2))
#define COMPUTEKT(n, KT) {                                                     \
        u32x4 pa01, pa02, pa12;                                                \
        _Pragma("unroll")                                                      \
        for (int j = 0; j < 4; ++j) {                                          \
            __half2 x0 = __hfma2(h2(n##b0[j]), W0, __hmul2(h2(n##a0[j]), OM0));\
            __half2 x1 = __hfma2(h2(n##b1[j]), W1, __hmul2(h2(n##a1[j]), OM1));\
            __half2 x2 = __hfma2(h2(n##b2[j]), W2, __hmul2(h2(n##a2[j]), OM2));\
            pa01[j] = h2u(__hmul2(x0, x1));                                    \
            pa02[j] = h2u(__hmul2(x0, x2));                                    \
            pa12[j] = h2u(__hmul2(x1, x2));                                    \
        }                                                                      \
        f16x8 fa01 = __builtin_bit_cast(f16x8, pa01);                          \
        f16x8 fa02 = __builtin_bit_cast(f16x8, pa02);                          \
        f16x8 fa12 = __builtin_bit_cast(f16x8, pa12);                          \
        acc00 = __builtin_amdgcn_mfma_f32_16x16x32_f16(__builtin_bit_cast(f16x8, wb[(0 * 6 + (KT)) * 64 + lane]), fa01, acc00, 0, 0, 0); \
        acc01 = __builtin_amdgcn_mfma_f32_16x16x32_f16(__builtin_bit_cast(f16x8, wb[(1 * 6 + (KT)) * 64 + lane]), fa01, acc01, 0, 0, 0); \
        acc10 = __builtin_amdgcn_mfma_f32_16x16x32_f16(__builtin_bit_cast(f16x8, wb[(2 * 6 + (KT)) * 64 + lane]), fa02, acc10, 0, 0, 0); \
        acc11 = __builtin_amdgcn_mfma_f32_16x16x32_f16(__builtin_bit_cast(f16x8, wb[(3 * 6 + (KT)) * 64 + lane]), fa02, acc11, 0, 0, 0); \
        acc20 = __builtin_amdgcn_mfma_f32_16x16x32_f16(__builtin_bit_cast(f16x8, wb[(4 * 6 + (KT)) * 64 + lane]), fa12, acc20, 0, 0, 0); \
        acc21 = __builtin_amdgcn_mfma_f32_16x16x32_f16(__builtin_bit_cast(f16x8, wb[(5 * 6 + (KT)) * 64 + lane]), fa12, acc21, 0, 0, 0); }

        DECL_LD(q0); DECL_LD(q1); DECL_LD(q2);
        DECL_LD(q3); DECL_LD(q4); DECL_LD(q5);

        // Issue ALL 36 gathers, then one merged fence = one exposed latency.
        LOADKT(q0, 0); LOADKT(q1, 1); LOADKT(q2, 2);
        LOADKT(q3, 3); LOADKT(q4, 4); LOADKT(q5, 5);
        KEEP36();

        COMPUTEKT(q0, 0);
        COMPUTEKT(q1, 1);
        COMPUTEKT(q2, 2);
        COMPUTEKT(q3, 3);
        COMPUTEKT(q4, 4);
        COMPUTEKT(q5, 5);

#undef DECL_LD
#undef LOADKT
#undef KEEP36
#undef COMPUTEKT

        // Epilogue (R8): 6 float4 stores, per-point-contiguous 64B segments.
        {
            float* o = out + (size_t)(base + row) * 96 + h * 4;
            *(f4*)(o + 0)  = acc00;
            *(f4*)(o + 16) = acc01;
            *(f4*)(o + 32) = acc10;
            *(f4*)(o + 48) = acc11;
            *(f4*)(o + 64) = acc20;
            *(f4*)(o + 80) = acc21;
        }
    }
}

extern "C" void kernel_launch(void* const* d_in, const int* in_sizes, int n_in,
                              void* d_out, int out_size, void* d_ws, size_t ws_size,
                              hipStream_t stream) {
    const float* pts = (const float*)d_in[0];
    const int* topk_id = (const int*)d_in[1];
    const float* tw = (const float*)d_in[2];
    const float* line0 = (const float*)d_in[3];
    const float* line1 = (const float*)d_in[4];
    const float* line2 = (const float*)d_in[5];
    const float* feat0 = (const float*)d_in[6];
    const float* feat1 = (const float*)d_in[7];
    const float* feat2 = (const float*)d_in[8];
    float* out = (float*)d_out;
    unsigned short* ws = (unsigned short*)d_ws;

    pack_kernel<<<512, 256, 0, stream>>>(topk_id, tw, line0, line1, line2,
                                         feat0, feat1, feat2, ws);
    main_kernel<<<NPTS / (64 * TPB_TILES), 256, 0, stream>>>(pts, ws, out);
}